// Round 1
// baseline (185.270 us; speedup 1.0000x reference)
//
#include <hip/hip_runtime.h>

// PSAMask collect: out[nh,nw,h,w] = x[nh-h+48, nw-w+48, h, w] (valid window, else 0)
// B=1, C=97*97=9409, H=W=97.  Pure permutation + zero-fill -> memory-bound.
//
// One block per (nh, h): stage input plane (a = nh-h+48 fixed, all b, all w)
// into LDS coalesced, then write output plane (all nw, all w) coalesced,
// reading LDS along the diagonal b = nw - w + 48. LDS stride 98 -> conflict-free.

#define HW97   97
#define PLANE  9409      // 97*97
#define HALF   48
#define LDSTR  98        // padded leading dim
#define NTHREADS 256

__global__ __launch_bounds__(NTHREADS)
void psamask_collect_kernel(const float* __restrict__ x, float* __restrict__ out) {
    const int h  = blockIdx.x;   // 0..96
    const int nh = blockIdx.y;   // 0..96
    const int a  = nh - h + HALF;
    const unsigned tid = threadIdx.x;

    // output slab base: channel row nh*97 .. nh*97+96, spatial row h
    float* __restrict__ outp = out + (size_t)(nh * HW97) * PLANE + h * HW97;

    if (a < 0 || a >= HW97) {
        // vh invalid: entire (nh, h) slab is zero
        for (unsigned idx = tid; idx < PLANE; idx += NTHREADS) {
            unsigned nw = idx / HW97;          // magic-mul div by const
            unsigned w  = idx - nw * HW97;
            outp[(size_t)nw * PLANE + w] = 0.0f;
        }
        return;
    }

    __shared__ float lds[HW97 * LDSTR];        // 97*98*4 = 38,024 B

    // stage: x[(a*97 + b)][h][w] for b,w in [0,97)^2 -> lds[b*98 + w]
    const float* __restrict__ xp = x + (size_t)(a * HW97) * PLANE + h * HW97;
    for (unsigned idx = tid; idx < PLANE; idx += NTHREADS) {
        unsigned b = idx / HW97;
        unsigned w = idx - b * HW97;
        lds[b * LDSTR + w] = xp[(size_t)b * PLANE + w];
    }
    __syncthreads();

    // write: out[nh*97+nw][h][w] = lds[(nw - w + 48)*98 + w] if valid else 0
    for (unsigned idx = tid; idx < PLANE; idx += NTHREADS) {
        unsigned nw = idx / HW97;
        unsigned w  = idx - nw * HW97;
        int b = (int)nw - (int)w + HALF;
        float v = (b >= 0 && b < HW97) ? lds[b * LDSTR + w] : 0.0f;
        outp[(size_t)nw * PLANE + w] = v;
    }
}

extern "C" void kernel_launch(void* const* d_in, const int* in_sizes, int n_in,
                              void* d_out, int out_size, void* d_ws, size_t ws_size,
                              hipStream_t stream) {
    const float* x = (const float*)d_in[0];
    float* out = (float*)d_out;
    dim3 grid(HW97, HW97);   // (h, nh)
    psamask_collect_kernel<<<grid, NTHREADS, 0, stream>>>(x, out);
}

// Round 2
// 184.218 us; speedup vs baseline: 1.0057x; 1.0057x over previous
//
#include <hip/hip_runtime.h>

// PSAMask collect: out[nh*97+nw][h][w] = x[(nh-h+48)*97 + (nw-w+48)][h][w]
// (valid window, else 0). B=1, C=9409, H=W=97. Pure permutation -> memory-bound.
//
// Block (h, nh): stage input plane x[a=nh-h+48][b][h][w] (b,w in [0,97)^2)
// directly into LDS via global_load_lds (async DMA, no VGPR round trip).
// LDS layout is SOURCE-swizzled: lds[b*97 + (w+b)%97] = x[b][w], so the
// diagonal read b = nw-w+48 hits address b*97 + (nw+48)%97 -> lane-to-lane
// bank delta = -97 mod 32 = -1 -> conflict-free without padding.

#define HW    97
#define PLANE 9409       // 97*97
#define HALF  48
#define NT    512
#define NITER 19         // ceil(9409/512); 9409 = 18*512 + 193

typedef const __attribute__((address_space(1))) void* gptr_t;
typedef __attribute__((address_space(3))) void* lptr_t;

__global__ __launch_bounds__(NT)
void psamask_collect_kernel(const float* __restrict__ x, float* __restrict__ out) {
    const int h  = blockIdx.x;   // 0..96
    const int nh = blockIdx.y;   // 0..96
    const int a  = nh - h + HALF;
    const unsigned tid = threadIdx.x;

    float* __restrict__ outp = out + (size_t)(nh * HW) * PLANE + h * HW;

    // tid = r0*97 + c0
    const unsigned r0 = tid / HW;          // 0..5 (one div, at entry)
    const unsigned c0 = tid - r0 * HW;

    if ((unsigned)a >= HW) {
        // vh invalid: whole (nh,h) slab is zero. Division-free walk.
        unsigned w   = c0;
        unsigned off = r0 * PLANE + c0;
        #pragma unroll
        for (int k = 0; k < NITER; ++k) {
            unsigned d = tid + (unsigned)k * NT;
            if (d < PLANE) outp[off] = 0.0f;
            w += 27;                               // 512 = 5*97 + 27
            bool wrap = (w >= HW);
            off += wrap ? (6u * PLANE - 70u) : (5u * PLANE + 27u);
            if (wrap) w -= HW;
        }
        return;
    }

    __shared__ float lds[PLANE];           // 36,836 B -> 4 blocks/CU, 32 waves/CU

    // ---- stage (async, direct to LDS): lds[b*97 + (w+b)%97] = xp[b*PLANE + w]
    const float* __restrict__ xp = x + (size_t)(a * HW) * PLANE + h * HW;
    {
        unsigned b = r0, cw = c0;          // flat dest d = b*97 + cw
        #pragma unroll
        for (int k = 0; k < NITER; ++k) {
            unsigned d = tid + (unsigned)k * NT;
            if (d < PLANE) {
                unsigned w = cw - b + ((cw < b) ? HW : 0u);   // (cw - b) mod 97
                const float* g = xp + b * PLANE + w;          // per-lane source
                unsigned d0 = (unsigned)k * NT + (tid & ~63u); // wave-uniform dest
                __builtin_amdgcn_global_load_lds((gptr_t)g, (lptr_t)&lds[d0], 4, 0, 0);
            }
            b += 5; cw += 27;
            if (cw >= HW) { cw -= HW; b += 1; }
        }
    }
    asm volatile("s_waitcnt vmcnt(0)" ::: "memory");
    __syncthreads();

    // ---- write: out[nw*PLANE + w] = (0<=b<97) ? lds[b*97 + (nw+48)%97] : 0
    {
        unsigned w   = c0;
        int      b   = (int)r0 - (int)c0 + HALF;             // nw - w + 48
        unsigned cw  = r0 + HALF; if (cw >= HW) cw -= HW;    // (nw+48) % 97
        unsigned off = r0 * PLANE + c0;
        #pragma unroll
        for (int k = 0; k < NITER; ++k) {
            unsigned d = tid + (unsigned)k * NT;
            if (d < PLANE) {
                bool valid = ((unsigned)b < HW);
                unsigned bc = valid ? (unsigned)b : 0u;      // clamp for safe read
                float v = lds[bc * HW + cw];
                outp[off] = valid ? v : 0.0f;
            }
            w += 27;
            bool wrap = (w >= HW);
            if (wrap) w -= HW;
            b  += wrap ? 76 : -22;
            cw += wrap ? 6u : 5u;
            if (cw >= HW) cw -= HW;
            off += wrap ? (6u * PLANE - 70u) : (5u * PLANE + 27u);
        }
    }
}

extern "C" void kernel_launch(void* const* d_in, const int* in_sizes, int n_in,
                              void* d_out, int out_size, void* d_ws, size_t ws_size,
                              hipStream_t stream) {
    const float* x = (const float*)d_in[0];
    float* out = (float*)d_out;
    dim3 grid(HW, HW);   // (h, nh)
    psamask_collect_kernel<<<grid, NT, 0, stream>>>(x, out);
}

// Round 4
// 179.884 us; speedup vs baseline: 1.0299x; 1.0241x over previous
//
#include <hip/hip_runtime.h>

// PSAMask collect: out[(nh*97+nw)*9409 + h*97 + w] = x[(nh-h+48)*97 + (nw-w+48)][h][w]
// (valid window, else 0). Pure permutation -> memory-bound.
//
// Block = (nh, h-chunk of 6..7): per h, stage input plane a = nh-h+48 into LDS
// (global_load_lds DMA), then write one h-row of all 97 (nh,nw) channels.
// Across the chunk, each output channel receives a CONTIGUOUS TH*388B run
// owned exclusively by this block -> full-line HBM writes, no cross-XCD
// false sharing (only ~16 chunk-seam lines per channel).
// LDS is source-swizzled: lds[b*97 + (w+b)%97] = x[b][w], so the diagonal
// read b = nw-w+48 has lane-to-lane bank delta -1 -> conflict-free unpadded.
// Sync: full vmcnt(0) + __syncthreads per row (no counted-vmcnt; R3's counted
// scheme raced on the wave-divergent tail iteration).

#define HW    97
#define PLANE 9409       // 97*97
#define HALF  48
#define NT    512
#define NITER 19         // ceil(9409/512); 9409 = 18*512 + 193

typedef const __attribute__((address_space(1))) void* gptr_t;
typedef __attribute__((address_space(3))) void* lptr_t;

__global__ __launch_bounds__(NT)
void psamask_collect_kernel(const float* __restrict__ x, float* __restrict__ out) {
    const int nh = blockIdx.x;          // 0..96
    const int c  = blockIdx.y;          // 0..15  (h-chunks: sizes 7,6,6,...,6)
    const int h0 = (c == 0) ? 0 : 7 + (c - 1) * 6;
    const int TH = (c == 0) ? 7 : 6;
    const unsigned tid = threadIdx.x;

    const unsigned r0 = tid / HW;       // 0..5
    const unsigned c0 = tid - r0 * HW;

    __shared__ float lds[PLANE];        // 36,836 B -> 4 blocks/CU

    for (int t = 0; t < TH; ++t) {
        const int h = h0 + t;
        const int a = nh - h + HALF;
        const bool avalid = ((unsigned)a < HW);

        if (t) __syncthreads();         // prev row's LDS reads done before overwrite

        // ---- stage plane (a fixed, all b,w): lds[b*97 + (w+b)%97] = xp[b*PLANE + w]
        if (avalid) {
            const float* __restrict__ xp =
                x + (size_t)((unsigned)a * HW) * PLANE + (unsigned)h * HW;
            unsigned b = r0, cw = c0;   // flat dest d = b*97 + cw
            #pragma unroll
            for (int k = 0; k < NITER; ++k) {
                unsigned d = tid + (unsigned)k * NT;
                if (d < PLANE) {
                    unsigned w = cw - b + ((cw < b) ? HW : 0u);   // (cw-b) mod 97
                    const float* g = xp + b * PLANE + w;          // per-lane source
                    unsigned d0 = (unsigned)k * NT + (tid & ~63u); // wave-uniform dest
                    __builtin_amdgcn_global_load_lds((gptr_t)g, (lptr_t)&lds[d0], 4, 0, 0);
                }
                b += 5; cw += 27;        // 512 = 5*97 + 27
                if (cw >= HW) { cw -= HW; b += 1; }
            }
        }
        asm volatile("s_waitcnt vmcnt(0)" ::: "memory");
        __syncthreads();

        // ---- write row h of all channels: outp[nw*PLANE + w]
        {
            float* __restrict__ outp =
                out + (size_t)((unsigned)nh * HW) * PLANE + (unsigned)h * HW;
            unsigned w   = c0;
            int      b   = (int)r0 - (int)c0 + HALF;             // nw - w + 48
            unsigned cw  = r0 + HALF; if (cw >= HW) cw -= HW;    // (nw+48) % 97
            unsigned off = r0 * PLANE + c0;
            #pragma unroll
            for (int k = 0; k < NITER; ++k) {
                unsigned d = tid + (unsigned)k * NT;
                if (d < PLANE) {
                    bool valid = avalid && ((unsigned)b < HW);
                    unsigned bc = ((unsigned)b < HW) ? (unsigned)b : 0u;
                    float v = lds[bc * HW + cw];
                    outp[off] = valid ? v : 0.0f;
                }
                w += 27;
                bool wrap = (w >= HW);
                if (wrap) w -= HW;
                b  += wrap ? 76 : -22;
                cw += wrap ? 6u : 5u;
                if (cw >= HW) cw -= HW;
                off += wrap ? (6u * PLANE - 70u) : (5u * PLANE + 27u);
            }
        }
    }
}

extern "C" void kernel_launch(void* const* d_in, const int* in_sizes, int n_in,
                              void* d_out, int out_size, void* d_ws, size_t ws_size,
                              hipStream_t stream) {
    const float* x = (const float*)d_in[0];
    float* out = (float*)d_out;
    dim3 grid(HW, 16);   // (nh, h-chunk)
    psamask_collect_kernel<<<grid, NT, 0, stream>>>(x, out);
}